// Round 1
// baseline (622.400 us; speedup 1.0000x reference)
//
#include <hip/hip_runtime.h>

// Fused tanh-RNN: h_{t+1} = tanh(x_t @ W_ih^T + b_ih + b_hh + h_t @ W_hh^T)
// out = h_T @ W_out^T + b_out
// B=4096, T=512, I=28, H=64, O=10. One wave owns 16 batch rows for all T
// (batch rows are independent -> no inter-block sync ever needed).
// All matmuls via v_mfma_f32_16x16x32_bf16 with hi/lo bf16 operand splitting
// (bf16x3: Ahi*Bhi + Alo*Bhi + Ahi*Blo) => ~2^-16 relative error per step.

#define T_STEPS 512
#define I_DIM   28
#define H_DIM   64
#define O_DIM   10
#define ROWS    16
#define LDSS    20   // dword stride of transposed h buffer: 80B, 16B-aligned, 2-way-free write banks

typedef __attribute__((ext_vector_type(8))) short bfrag;   // 8 x bf16 (4 VGPRs)
typedef __attribute__((ext_vector_type(4))) float ffrag;   // MFMA C/D
typedef __attribute__((ext_vector_type(4))) float float4v;

#define MFMA(a,b,c) __builtin_amdgcn_mfma_f32_16x16x32_bf16((a),(b),(c),0,0,0)

// Split fp32 -> bf16 hi + bf16 lo (v = hi + lo exactly up to ~2^-16 rel).
// Truncation for hi is fine: lo captures the remainder exactly (Sterbenz),
// lo's own truncation error is <= 2^-16 * |v|.
__device__ __forceinline__ void split8(const float* v, bfrag& hi, bfrag& lo){
#pragma unroll
  for (int i = 0; i < 8; i++){
    unsigned u = __float_as_uint(v[i]);
    hi[i] = (short)(u >> 16);
    float rem = v[i] - __uint_as_float(u & 0xffff0000u);
    lo[i] = (short)(__float_as_uint(rem) >> 16);
  }
}

__device__ __forceinline__ float fast_tanh(float p){
  // tanh(p) = 1 - 2/(exp2(2*log2e*p)+1); v_exp/v_rcp are ~1ulp, saturates
  // correctly at +-inf arguments.
#if __has_builtin(__builtin_amdgcn_exp2f) && __has_builtin(__builtin_amdgcn_rcpf)
  float e = __builtin_amdgcn_exp2f(p * 2.88539008177792681f);
  return 1.0f - 2.0f * __builtin_amdgcn_rcpf(e + 1.0f);
#else
  float e = __exp2f(p * 2.88539008177792681f);
  return 1.0f - 2.0f / (e + 1.0f);
#endif
}

__global__ __launch_bounds__(64, 1) void rnn_fused(
    const float* __restrict__ x,
    const float* __restrict__ W_ih,
    const float* __restrict__ W_hh,
    const float* __restrict__ b_ih,
    const float* __restrict__ b_hh,
    const float* __restrict__ W_out,
    const float* __restrict__ b_out,
    float* __restrict__ out)
{
  __shared__ float hT[H_DIM * LDSS];   // h transposed: hT[k][r], r = batch row in tile
  const int lane = threadIdx.x;        // 64 threads = 1 wave
  const int c = lane & 15;             // A-frag row / B-frag col / C-frag col
  const int q = lane >> 4;             // quad: k-group for A/B frags, row-group for C
  const int rowbase = blockIdx.x * ROWS;

  // ---- hoist W_hh^T as B-fragments (hi/lo), [n-tile][k-tile] ----
  // B[k][n] fragment: n = lane&15 (+16*nt), k = q*8+jj (+32*kt)
  // B[k][j] = W_hh^T[k][j] = W_hh[j][k]  -> 8 consecutive floats of row j.
  bfrag whh_hi[4][2], whh_lo[4][2];
#pragma unroll
  for (int nt = 0; nt < 4; ++nt){
#pragma unroll
    for (int kt = 0; kt < 2; ++kt){
      const float* p = W_hh + (c + 16*nt)*H_DIM + kt*32 + q*8;
      float4v a = *(const float4v*)p;
      float4v b = *(const float4v*)(p + 4);
      float v[8] = {a.x,a.y,a.z,a.w, b.x,b.y,b.z,b.w};
      split8(v, whh_hi[nt][kt], whh_lo[nt][kt]);
    }
  }

  // ---- W_ih^T as B-fragments, K padded 28 -> 32 with zeros ----
  bfrag wih_hi[4], wih_lo[4];
#pragma unroll
  for (int nt = 0; nt < 4; ++nt){
    const float* p = W_ih + (c + 16*nt)*I_DIM + q*8;
    float v[8];
    float4v a = *(const float4v*)p;       // i = q*8..q*8+3, valid for all q (max 27)
    v[0]=a.x; v[1]=a.y; v[2]=a.z; v[3]=a.w;
    if (q < 3){
      float4v b = *(const float4v*)(p + 4);
      v[4]=b.x; v[5]=b.y; v[6]=b.z; v[7]=b.w;
    } else {
      v[4]=v[5]=v[6]=v[7]=0.f;            // i = 28..31 pad
    }
    split8(v, wih_hi[nt], wih_lo[nt]);
  }

  // bias per output column j = c + 16*nt (same for all 4 C regs)
  float bias[4];
#pragma unroll
  for (int nt = 0; nt < 4; ++nt) bias[nt] = b_ih[c + 16*nt] + b_hh[c + 16*nt];

  // ---- h state as A-fragments (hi/lo), h0 = 0 ----
  bfrag h_hi[2], h_lo[2];
#pragma unroll
  for (int kt = 0; kt < 2; ++kt){
#pragma unroll
    for (int i = 0; i < 8; i++){ h_hi[kt][i] = 0; h_lo[kt][i] = 0; }
  }

  // x loaded directly in A-frag pattern: row r = c, i = q*8 + jj.
  // quad 3's upper float4 (i=28..31) multiplies zero W_ih pad, so its value is
  // irrelevant — clamp the pointer instead of masking the load (stays in-bounds).
  const float* xp = x + ((size_t)(rowbase + c) * T_STEPS) * I_DIM + q*8;
  float4v xa = *(const float4v*)xp;
  float4v xb = *(const float4v*)(q < 3 ? xp + 4 : xp);

  for (int t = 0; t < T_STEPS; ++t){
    // prefetch x for t+1 (register double-buffer hides HBM latency)
    const float* xn = (t < T_STEPS - 1) ? (xp + I_DIM) : xp;
    float4v na = *(const float4v*)xn;
    float4v nb = *(const float4v*)(q < 3 ? xn + 4 : xn);

    float xv[8] = {xa.x,xa.y,xa.z,xa.w, xb.x,xb.y,xb.z,xb.w};
    bfrag xhi, xlo;
    split8(xv, xhi, xlo);

    ffrag acc[4];
#pragma unroll
    for (int nt = 0; nt < 4; ++nt){
      acc[nt].x = bias[nt]; acc[nt].y = bias[nt];
      acc[nt].z = bias[nt]; acc[nt].w = bias[nt];
    }

    // input projection: P += x @ W_ih^T   (bf16x3)
#pragma unroll
    for (int nt = 0; nt < 4; ++nt){
      acc[nt] = MFMA(xhi, wih_hi[nt], acc[nt]);
      acc[nt] = MFMA(xlo, wih_hi[nt], acc[nt]);
      acc[nt] = MFMA(xhi, wih_lo[nt], acc[nt]);
    }
    // recurrence: P += h @ W_hh^T        (bf16x3)
#pragma unroll
    for (int nt = 0; nt < 4; ++nt){
#pragma unroll
      for (int kt = 0; kt < 2; ++kt){
        acc[nt] = MFMA(h_hi[kt], whh_hi[nt][kt], acc[nt]);
        acc[nt] = MFMA(h_lo[kt], whh_hi[nt][kt], acc[nt]);
        acc[nt] = MFMA(h_hi[kt], whh_lo[nt][kt], acc[nt]);
      }
    }

    // tanh, then transposed LDS store: C layout gives lane 4 consecutive batch
    // rows (m = q*4+reg) at one hidden col j = c+16*nt -> b128 write hT[j][q*4].
    __syncthreads();   // WAR: previous iteration's frag reads complete
#pragma unroll
    for (int nt = 0; nt < 4; ++nt){
      float4v hv;
      hv.x = fast_tanh(acc[nt].x);
      hv.y = fast_tanh(acc[nt].y);
      hv.z = fast_tanh(acc[nt].z);
      hv.w = fast_tanh(acc[nt].w);
      *(float4v*)&hT[(c + 16*nt)*LDSS + q*4] = hv;
    }
    __syncthreads();   // RAW: writes visible before A-frag reload

    // reload h as A-fragments: lane needs h[r=c][k=kt*32+q*8+jj]
#pragma unroll
    for (int kt = 0; kt < 2; ++kt){
      float hv[8];
#pragma unroll
      for (int jj = 0; jj < 8; ++jj) hv[jj] = hT[(kt*32 + q*8 + jj)*LDSS + c];
      split8(hv, h_hi[kt], h_lo[kt]);
    }

    xa = na; xb = nb; xp = xn;
  }

  __syncthreads();
  // epilogue: out[r][o] = b_out[o] + sum_k h[r][k] * W_out[o][k]
  // lanes: r = c, o = q, q+4, q+8 (o < 10); tiny, fp32 VALU, once per block.
  for (int oo = q; oo < O_DIM; oo += 4){
    float s = b_out[oo];
    for (int k = 0; k < H_DIM; ++k)
      s += hT[k*LDSS + c] * W_out[oo*H_DIM + k];
    out[(size_t)(rowbase + c)*O_DIM + oo] = s;
  }
}

extern "C" void kernel_launch(void* const* d_in, const int* in_sizes, int n_in,
                              void* d_out, int out_size, void* d_ws, size_t ws_size,
                              hipStream_t stream) {
  const float* x     = (const float*)d_in[0];
  const float* W_ih  = (const float*)d_in[1];
  const float* W_hh  = (const float*)d_in[2];
  const float* b_ih  = (const float*)d_in[3];
  const float* b_hh  = (const float*)d_in[4];
  const float* W_out = (const float*)d_in[5];
  const float* b_out = (const float*)d_in[6];
  float* out = (float*)d_out;

  int B = in_sizes[0] / (T_STEPS * I_DIM);   // 4096
  rnn_fused<<<B / ROWS, 64, 0, stream>>>(x, W_ih, W_hh, b_ih, b_hh, W_out, b_out, out);
}